// Round 1
// baseline (98.606 us; speedup 1.0000x reference)
//
#include <hip/hip_runtime.h>
#include <math.h>

#define W 512
#define H 512
#define NUM_R 725
#define NUM_T 180
#define RCHUNK 128   // n-samples per block (gridDim.y = 512/128 = 4)
#define ROWS 16      // rows staged in LDS per barrier pair (16*512*4B = 32 KB)

// ---------------------------------------------------------------------------
// Transpose 512x512 f32: imgT[n*W + x] = img[x*W + n]
// ---------------------------------------------------------------------------
__global__ __launch_bounds__(256) void transpose_k(const float* __restrict__ in,
                                                   float* __restrict__ out) {
    __shared__ float tile[32][33];
    const int bx = blockIdx.x * 32, by = blockIdx.y * 32;
    const int tx = threadIdx.x, ty = threadIdx.y;  // block (32, 8)
#pragma unroll
    for (int j = 0; j < 32; j += 8)
        tile[ty + j][tx] = in[(size_t)(by + ty + j) * W + (bx + tx)];
    __syncthreads();
#pragma unroll
    for (int j = 0; j < 32; j += 8)
        out[(size_t)(bx + ty + j) * H + (by + tx)] = tile[tx][ty + j];
}

// ---------------------------------------------------------------------------
// Hough accumulation.
// For theta t: use_x = |sin|>=|cos|.
//   x-sweep: y = rint((rho - n*cos)/sin), add img[n*W + y]   (row n of img)
//   y-sweep: x = rint((rho - n*sin)/cos), add img[x*W + n]   (row n of imgT)
// Both become gathers into LDS-staged "row n" of (img or imgT).
// f64 coordinate math mirrors the numpy reference (round-half-even).
// ---------------------------------------------------------------------------
__global__ __launch_bounds__(256) void hough_k(const float* __restrict__ img,
                                               const float* __restrict__ imgT,
                                               float* __restrict__ out,
                                               int hasT) {
    const int t   = blockIdx.x;            // theta index 0..179
    const int n0  = blockIdx.y * RCHUNK;   // n-chunk base
    const int tid = threadIdx.x;

    __shared__ float lds[ROWS * W];

    // ---- per-theta constants (f64, mirroring numpy) ----
    const double theta = (double)t * (M_PI / 180.0);
    const double s = sin(theta);
    const double c = cos(theta);
    const bool use_x = fabs(s) >= fabs(c);
    double dd = use_x ? s : c;             // divisor
    if (fabs(dd) < 1e-6) dd = 1.0;         // sin_safe / cos_safe guard (mirrors ref)
    const double a   = use_x ? c : s;      // multiplier of n
    const double inv = 1.0 / dd;
    const double nk2 = -(a * inv);         // y_f = rho*inv + n*nk2

    const double diag = sqrt(524288.0);          // sqrt(W*W + H*H) in f64
    const double step = (2.0 * diag) / 724.0;    // np.linspace step

    // ---- this thread's three rho bins: r = tid, tid+256, tid+512 ----
    const int r1 = tid, r2 = tid + 256, r3 = tid + 512;
    const int r3c = (r3 < NUM_R) ? r3 : (NUM_R - 1);

    // np.linspace: rho = r*step - diag, endpoint forced to +diag
    double rho1 = (double)r1 * step - diag;
    double rho2 = (double)r2 * step - diag;
    double rho3 = (double)r3c * step - diag;
    if (r1 == NUM_R - 1) rho1 = diag;
    if (r2 == NUM_R - 1) rho2 = diag;
    if (r3c == NUM_R - 1) rho3 = diag;

    const double k1a = rho1 * inv;
    const double k1b = rho2 * inv;
    const double k1c = rho3 * inv;

    const float* base = use_x ? img : imgT;

    float acc1 = 0.f, acc2 = 0.f, acc3 = 0.f;

    for (int j0 = 0; j0 < RCHUNK; j0 += ROWS) {
        const int nbase = n0 + j0;
        // ---- stage ROWS rows into LDS ----
        if (use_x || hasT) {
            // contiguous rows of base: fully coalesced float4 loads
            const float4* src = (const float4*)(base + (size_t)nbase * W);
            float4* dst = (float4*)lds;
#pragma unroll
            for (int i = 0; i < (ROWS * W / 4) / 256; ++i)
                dst[tid + i * 256] = src[tid + i * 256];
        } else {
            // fallback (no workspace for transpose): strided column loads
            for (int i = tid; i < ROWS * W; i += 256) {
                const int j = i >> 9;          // row within stage
                const int x = i & (W - 1);
                lds[i] = img[(size_t)x * W + (nbase + j)];
            }
        }
        __syncthreads();

#pragma unroll
        for (int j = 0; j < ROWS; ++j) {
            const double nn = (double)(nbase + j);
            const double yf1 = fma(nn, nk2, k1a);
            const double yf2 = fma(nn, nk2, k1b);
            const double yf3 = fma(nn, nk2, k1c);
            const int y1 = __double2int_rn(yf1);   // round-half-even, matches np.round
            const int y2 = __double2int_rn(yf2);
            const int y3 = __double2int_rn(yf3);
            const float* row = lds + j * W;
            const int y1c = min(max(y1, 0), W - 1);
            const int y2c = min(max(y2, 0), W - 1);
            const int y3c = min(max(y3, 0), W - 1);
            const float v1 = row[y1c];
            const float v2 = row[y2c];
            const float v3 = row[y3c];
            acc1 += ((unsigned)y1 < (unsigned)W) ? v1 : 0.f;
            acc2 += ((unsigned)y2 < (unsigned)W) ? v2 : 0.f;
            acc3 += ((unsigned)y3 < (unsigned)W) ? v3 : 0.f;
        }
        __syncthreads();
    }

    // ---- accumulate partials (4 n-chunks per (r,t)) ----
    atomicAdd(&out[(size_t)r1 * NUM_T + t], acc1);
    atomicAdd(&out[(size_t)r2 * NUM_T + t], acc2);
    if (r3 < NUM_R) atomicAdd(&out[(size_t)r3 * NUM_T + t], acc3);
}

extern "C" void kernel_launch(void* const* d_in, const int* in_sizes, int n_in,
                              void* d_out, int out_size, void* d_ws, size_t ws_size,
                              hipStream_t stream) {
    const float* img = (const float*)d_in[0];
    float* out = (float*)d_out;

    // d_out is poisoned before every timed call; zero it (atomic accumulation).
    hipMemsetAsync(d_out, 0, (size_t)NUM_R * NUM_T * sizeof(float), stream);

    const int hasT = (ws_size >= (size_t)W * H * sizeof(float)) ? 1 : 0;
    float* imgT = (float*)d_ws;
    if (hasT) {
        transpose_k<<<dim3(16, 16), dim3(32, 8), 0, stream>>>(img, imgT);
    }

    hough_k<<<dim3(NUM_T, W / RCHUNK), dim3(256), 0, stream>>>(
        img, hasT ? imgT : img, out, hasT);
}